// Round 3
// baseline (195.960 us; speedup 1.0000x reference)
//
#include <hip/hip_runtime.h>

#define N_ANCHORS 5000
#define N_CLASSES 80
#define OUT_COLS  84
#define MAX_BOXES 300
#define SCORE_THR 0.05f

#define LK_PAD    5120
#define NB        4096
#define BLOCK     1024
#define SLOTS     4            // ring of 128-candidate steps
#define DONEP     0x40000000u
#define NIW       6            // intra workers: wv 1..6
#define NSW       9            // sweeps: wv 7..15

typedef unsigned long long u64;
typedef unsigned int u32;
typedef unsigned short u16;

#define WG __HIP_MEMORY_SCOPE_WORKGROUP

__device__ __forceinline__ float readlane_f(float v, int l) {
    return __int_as_float(__builtin_amdgcn_readlane(__float_as_int(v), l));
}
__device__ __forceinline__ u64 readlane_u64(u64 v, int l) {
    u32 lo = (u32)__builtin_amdgcn_readlane((int)(u32)v, l);
    u32 hi = (u32)__builtin_amdgcn_readlane((int)(u32)(v >> 32), l);
    return ((u64)hi << 32) | lo;
}
__device__ __forceinline__ float4 bcast4(float4 b, int q) {
    float4 o;
    o.x = readlane_f(b.x, q); o.y = readlane_f(b.y, q);
    o.z = readlane_f(b.z, q); o.w = readlane_f(b.w, q);
    return o;
}
__device__ __forceinline__ u64 aload64(u64* p) {
    return __hip_atomic_load(p, __ATOMIC_ACQUIRE, WG);
}
// monotone score->bucket map; mirrored so step 0 = HIGHEST scores
__device__ __forceinline__ int bucket_of(float s) {
    float u = sqrtf(s);
    int b = (int)((u - 0.2236f) * 5275.0f);
    return (NB - 1) - min(max(b, 0), NB - 1);
}
// IoU(a,q) > 0.5  <=>  3*inter > aa+aq ; sentinel q (1e9^4, aq=1e18) -> false
__device__ __forceinline__ bool iou3(float4 a, float aa, float4 q, float aq) {
    float iw = fmaxf(fminf(a.z, q.z) - fmaxf(a.x, q.x), 0.0f);
    float ih = fmaxf(fminf(a.w, q.w) - fmaxf(a.y, q.y), 0.0f);
    return 3.0f * (iw * ih) > aa + aq;
}

// LDS: lk[5120]u64 @0..40960 | hist[4096]u32 @40960..57344 (post-sort aliased:
//   Iring 4*64*2 u64 @40960 | Bring 4*128 f4 @45056 | kout16 304 u16 @53248
//   | KS 4*2 u64 @53856)
// | kbox 304 f4 @57344 | karea 304 f32 @62208 | wtot 16 u32 @63424
// | flagIK 4 u64 @63488 {lo=flagK, hi=flagI} | progcnt u64 @63520 {lo=prog, hi=kcnt}
__global__ __launch_bounds__(BLOCK, 1) void nms(const float* __restrict__ cls,
                                                const float4* __restrict__ boxes4,
                                                float* __restrict__ out) {
    __shared__ __align__(16) char SMEM[63552];
    u64*    lk      = (u64*)SMEM;
    u32*    hist    = (u32*)(SMEM + 40960);
    u64*    Iring   = (u64*)(SMEM + 40960);
    float4* Bring   = (float4*)(SMEM + 45056);
    u16*    kout16  = (u16*)(SMEM + 53248);
    u64*    KS      = (u64*)(SMEM + 53856);
    float4* kbox    = (float4*)(SMEM + 57344);   // 304 slots, sentinel-padded
    float*  karea   = (float*)(SMEM + 62208);    // kept areas, sentinel 1e18
    u32*    wtot    = (u32*)(SMEM + 63424);
    u64*    flagIK  = (u64*)(SMEM + 63488);
    u32*    flagIK32= (u32*)(SMEM + 63488);
    u64*    progcnt = (u64*)(SMEM + 63520);

    const int c = blockIdx.x;
    const int t = threadIdx.x;
    const int lane = t & 63;
    const int wv = t >> 6;
    const float* boxesf = (const float*)boxes4;

    // ---------- fused prep ----------
    u32 sb[5];
    #pragma unroll
    for (int m = 0; m < 5; ++m) {
        int j = m * BLOCK + t;
        float v = (j < N_ANCHORS) ? cls[(size_t)j * N_CLASSES + c] : 0.0f;
        sb[m] = (v > SCORE_THR) ? __float_as_uint(v) : 0u;
    }
    for (int i = t; i < N_ANCHORS; i += BLOCK)
        out[(size_t)i * OUT_COLS + 4 + c] = 0.0f;
    if (c < 4)
        for (int i = t; i < N_ANCHORS; i += BLOCK)
            out[(size_t)i * OUT_COLS + c] = boxesf[(size_t)i * 4 + c];

    // ---------- sort phase (all 16 waves) ----------
    for (int b = t; b < NB; b += BLOCK) hist[b] = 0u;
    if (t < 304) { kbox[t] = make_float4(1e9f, 1e9f, 1e9f, 1e9f); karea[t] = 1e18f; }
    if (t < SLOTS) flagIK[t] = 0ull;
    if (t == 0) *progcnt = 0ull;
    __syncthreads();
    #pragma unroll
    for (int m = 0; m < 5; ++m)
        if (sb[m]) atomicAdd(&hist[bucket_of(__uint_as_float(sb[m]))], 1u);
    __syncthreads();

    const int hbase = t * 4;
    u32 vals[4]; u32 run = 0;
    #pragma unroll
    for (int k = 0; k < 4; ++k) { run += hist[hbase + k]; vals[k] = run; }
    u32 x = run;
    #pragma unroll
    for (int off = 1; off < 64; off <<= 1) { u32 y = __shfl_up(x, off); if (lane >= off) x += y; }
    if (lane == 63) wtot[wv] = x;
    __syncthreads();
    u32 woff = 0;
    for (int w = 0; w < wv; ++w) woff += wtot[w];
    const u32 exb = woff + x - run;
    #pragma unroll
    for (int k = 0; k < 4; ++k) hist[hbase + k] = exb + (k ? vals[k - 1] : 0u);
    __syncthreads();
    #pragma unroll
    for (int m = 0; m < 5; ++m) {
        if (sb[m]) {
            int j = m * BLOCK + t;
            u32 pos = atomicAdd(&hist[bucket_of(__uint_as_float(sb[m]))], 1u);
            lk[pos] = ((u64)sb[m] << 32) | (u32)(~(u32)j);
        }
    }
    __syncthreads();
    const int total = (int)hist[NB - 1];
    for (int v = total + t; v < LK_PAD; v += BLOCK) lk[v] = 0ull;
    for (int b = hbase; b < hbase + 4; ++b) {
        int s0 = b ? (int)hist[b - 1] : 0;
        int e  = (int)hist[b];
        for (int i = s0 + 1; i < e; ++i) {
            u64 key = lk[i]; int q = i - 1;
            while (q >= s0 && lk[q] < key) { lk[q + 1] = lk[q]; --q; }
            lk[q + 1] = key;
        }
    }
    __syncthreads();                    // LAST barrier; roles diverge
    const int nsteps = (total + 127) >> 7;

    if (wv >= 1 && wv <= NIW) {
        // ======= intra workers: AA and BB 64x64 matrices, compute PRE-gate =======
        for (int s = wv - 1; s < nsteps; s += NIW) {
            const int slot = s & (SLOTS - 1);
            u64 eA = lk[s * 128 + lane], eB = lk[s * 128 + 64 + lane];
            u32 jA = eA ? ~(u32)eA : 0u, jB = eB ? ~(u32)eB : 0u;
            float4 bA = boxes4[jA], bB = boxes4[jB];
            float aA = (bA.z - bA.x) * (bA.w - bA.y);
            float aB = (bB.z - bB.x) * (bB.w - bB.y);
            u64 AA = 0ull, BB = 0ull;
            #pragma unroll 16
            for (int q = 0; q < 64; ++q) {
                float4 oA = bcast4(bA, q); float qaA = readlane_f(aA, q);
                float4 oB = bcast4(bB, q); float qaB = readlane_f(aB, q);
                if (iou3(bA, aA, oA, qaA)) AA |= 1ull << q;
                if (iou3(bB, aB, oB, qaB)) BB |= 1ull << q;
            }
            u32 p;
            for (;;) {                                   // gate only guards the store
                p = (u32)aload64(progcnt);
                if ((int)p >= s - (SLOTS - 1)) break;
                __builtin_amdgcn_s_sleep(2);
            }
            if (p >= DONEP) return;
            Iring[(slot * 64 + lane) * 2]     = AA;
            Iring[(slot * 64 + lane) * 2 + 1] = BB;
            if (lane == 0)
                __hip_atomic_store(&flagIK32[slot * 2 + 1], (u32)(s + 1), __ATOMIC_RELEASE, WG);
        }
        return;
    }
    if (wv > NIW) {
        // ======= sweeps: 2 candidates/lane vs kept list, incremental top-up =======
        for (int s = wv - (NIW + 1); s < nsteps; s += NSW) {
            const int slot = s & (SLOTS - 1);
            u64 eA = lk[s * 128 + lane], eB = lk[s * 128 + 64 + lane];
            bool vA = (eA != 0ull), vB = (eB != 0ull);
            u32 jA = vA ? ~(u32)eA : 0u, jB = vB ? ~(u32)eB : 0u;
            float4 bA = boxes4[jA], bB = boxes4[jB];
            float aA = (bA.z - bA.x) * (bA.w - bA.y);
            float aB = (bB.z - bB.x) * (bB.w - bB.y);
            bool supA = !vA, supB = !vB;
            bool allsup = false;
            u64 pk = aload64(progcnt);                   // free probe
            u32 kn = (u32)(pk >> 32), done = 0;
            {   // pre-gate bulk vs published keeps
                u32 r1 = (kn + 3) & ~3u;
                for (u32 r = done; r < r1; r += 4) {
                    float4 q0 = kbox[r], q1 = kbox[r+1], q2 = kbox[r+2], q3 = kbox[r+3];
                    float4 a4 = *(const float4*)(karea + r);
                    supA = supA | iou3(bA,aA,q0,a4.x) | iou3(bA,aA,q1,a4.y)
                                | iou3(bA,aA,q2,a4.z) | iou3(bA,aA,q3,a4.w);
                    supB = supB | iou3(bB,aB,q0,a4.x) | iou3(bB,aB,q1,a4.y)
                                | iou3(bB,aB,q2,a4.z) | iou3(bB,aB,q3,a4.w);
                    if (((r >> 2) & 7u) == 7u && !__ballot(!(supA && supB))) { allsup = true; break; }
                }
                done = kn & ~3u;
            }
            for (;;) {                                   // slot-free gate
                pk = aload64(progcnt);
                if ((int)(u32)pk >= s - (SLOTS - 1)) break;
                __builtin_amdgcn_s_sleep(2);
            }
            if ((u32)pk >= DONEP) return;
            Bring[slot * 128 + lane] = bA;
            Bring[slot * 128 + 64 + lane] = bB;
            while (!allsup) {                            // incremental till prog >= s-1
                kn = (u32)(pk >> 32);
                u32 r1 = (kn + 3) & ~3u;
                for (u32 r = done; r < r1; r += 4) {
                    float4 q0 = kbox[r], q1 = kbox[r+1], q2 = kbox[r+2], q3 = kbox[r+3];
                    float4 a4 = *(const float4*)(karea + r);
                    supA = supA | iou3(bA,aA,q0,a4.x) | iou3(bA,aA,q1,a4.y)
                                | iou3(bA,aA,q2,a4.z) | iou3(bA,aA,q3,a4.w);
                    supB = supB | iou3(bB,aB,q0,a4.x) | iou3(bB,aB,q1,a4.y)
                                | iou3(bB,aB,q2,a4.z) | iou3(bB,aB,q3,a4.w);
                    if (((r >> 2) & 7u) == 7u && !__ballot(!(supA && supB))) { allsup = true; break; }
                }
                if (allsup) break;
                done = kn & ~3u;
                if ((int)(u32)pk >= s - 1) break;        // covered through step s-2
                pk = aload64(progcnt);                   // tight re-probe (near-critical)
            }
            u64 KSA = __ballot(supA), KSB = __ballot(supB);
            if (lane == 0) {
                KS[slot * 2] = KSA; KS[slot * 2 + 1] = KSB;
                __hip_atomic_store(&flagIK32[slot * 2], (u32)(s + 1), __ATOMIC_RELEASE, WG);
            }
            if ((u32)pk >= DONEP) return;
        }
        return;
    }

    // ======= wave 0: serial scan over 128-candidate steps =======
    int kept = 0; u32 kcur = 0; bool capped = false;
    u64 kmPrevA = 0ull, kmPrevB = 0ull;
    float4 bxPvA = make_float4(0,0,0,0), bxPvB = make_float4(0,0,0,0);
    float arPvA = 0.f, arPvB = 0.f;
    u64 keyA = lk[lane], keyB = lk[64 + lane];           // step-0 prefetch
    for (int s = 0; s < nsteps; ++s) {
        const int slot = s & (SLOTS - 1);
        bool vA = (keyA != 0ull), vB = (keyB != 0ull);

        const u64 want = ((u64)(u32)(s + 1) << 32) | (u32)(s + 1);
        while (aload64(&flagIK[slot]) != want) { }        // both flags, one probe
        u64 ksA = KS[slot * 2], ksB = KS[slot * 2 + 1];
        u64 kmA = 0ull, kmB = 0ull;
        if ((ksA & ksB) != ~0ull) {
            float4 bxA = Bring[slot * 128 + lane];
            float4 bxB = Bring[slot * 128 + 64 + lane];
            u64 IAA = Iring[(slot * 64 + lane) * 2];
            u64 IBB = Iring[(slot * 64 + lane) * 2 + 1];
            float arA = (bxA.z - bxA.x) * (bxA.w - bxA.y);
            float arB = (bxB.z - bxB.x) * (bxB.w - bxB.y);
            bool alA = vA && !((ksA >> lane) & 1ull);
            bool alB = vB && !((ksB >> lane) & 1ull);
            // register top-up: step s-1 keeps (sweep covered through s-2)
            u64 mk = kmPrevA;
            while (mk) {
                int p = __ffsll((long long)mk) - 1; mk &= mk - 1;
                float4 q = bcast4(bxPvA, p); float qa = readlane_f(arPvA, p);
                alA = alA && !iou3(bxA, arA, q, qa);
                alB = alB && !iou3(bxB, arB, q, qa);
            }
            mk = kmPrevB;
            while (mk) {
                int p = __ffsll((long long)mk) - 1; mk &= mk - 1;
                float4 q = bcast4(bxPvB, p); float qa = readlane_f(arPvB, p);
                alA = alA && !iou3(bxA, arA, q, qa);
                alB = alB && !iou3(bxB, arB, q, qa);
            }
            u64 remA = __ballot(alA), remB = __ballot(alB);
            while (remA | remB) {                         // greedy chain, position order
                if (remA) {
                    int p = __ffsll((long long)remA) - 1;
                    kmA |= 1ull << p;
                    if (++kept == MAX_BOXES) { capped = true; break; }
                    remA &= ~readlane_u64(IAA, p);
                    // cross A->B: broadcast kept A, test own B candidate
                    float4 q = bcast4(bxA, p); float qa = readlane_f(arA, p);
                    remB &= ~__ballot(iou3(bxB, arB, q, qa));
                } else {
                    int p = __ffsll((long long)remB) - 1;
                    kmB |= 1ull << p;
                    if (++kept == MAX_BOXES) { capped = true; break; }
                    remB &= ~readlane_u64(IBB, p);
                }
            }
            u32 cA = (u32)__popcll(kmA);
            if ((kmA >> lane) & 1ull) {
                int rk = (int)__popcll(kmA & ((1ull << lane) - 1ull));
                kbox[kcur + rk] = bxA; karea[kcur + rk] = arA;
                kout16[kcur + rk] = (u16)(s * 128 + lane);
            }
            if ((kmB >> lane) & 1ull) {
                int rk = (int)cA + (int)__popcll(kmB & ((1ull << lane) - 1ull));
                kbox[kcur + rk] = bxB; karea[kcur + rk] = arB;
                kout16[kcur + rk] = (u16)(s * 128 + 64 + lane);
            }
            kcur += cA + (u32)__popcll(kmB);
            bxPvA = bxA; arPvA = arA; bxPvB = bxB; arPvB = arB;
        }
        kmPrevA = kmA; kmPrevB = kmB;
        if (capped) break;
        if (lane == 0)                                    // one packed release
            __hip_atomic_store(progcnt, ((u64)kcur << 32) | (u32)(s + 1),
                               __ATOMIC_RELEASE, WG);
        int nb = (s + 1 < nsteps) ? (s + 1) * 128 : 0;    // guarded prefetch
        keyA = lk[nb + lane]; keyB = lk[nb + 64 + lane];
    }
    if (lane == 0)
        __hip_atomic_store(progcnt, ((u64)kcur << 32) | DONEP, __ATOMIC_RELEASE, WG);

    // flush buffered keeps to global (off the serial chain); score via lk
    for (u32 i = (u32)lane; i < kcur; i += 64) {
        u64 key = lk[kout16[i]];
        out[(size_t)(~(u32)key) * OUT_COLS + 4 + c] = __uint_as_float((u32)(key >> 32));
    }
}

extern "C" void kernel_launch(void* const* d_in, const int* in_sizes, int n_in,
                              void* d_out, int out_size, void* d_ws, size_t ws_size,
                              hipStream_t stream) {
    const float* cls = (const float*)d_in[1];
    float* out = (float*)d_out;
    nms<<<N_CLASSES, BLOCK, 0, stream>>>(cls, (const float4*)d_in[0], out);
}